// Round 9
// baseline (268.325 us; speedup 1.0000x reference)
//
#include <hip/hip_runtime.h>
#include <math.h>

#define BBATCH 64
#define LL 200
#define DD 300
#define PP 16
#define EPSV 1e-12f
#define PS 328      // LDS row stride in halfs (656 B); b128 reads spread 4 consecutive banks
#define NCH 10      // K chunks of 32 (K padded 300->320)

typedef _Float16 f16x8 __attribute__((ext_vector_type(8)));
typedef float f32x4v __attribute__((ext_vector_type(4)));

#define MFMA16(A, B, C) __builtin_amdgcn_mfma_f32_16x16x32_f16((A), (B), (C), 0, 0, 0)

// ---------------- ksq table: ksqt[((ch*4+quad)*16+p)*8+e] = f16(kp[p][ch*32+quad*8+e]^2)
__global__ __launch_bounds__(256) void ksq_kernel(const float* __restrict__ kern,
                                                  _Float16* __restrict__ ksqt) {
    for (int ent = threadIdx.x; ent < 640; ent += 256) {
        int p = ent & 15, quad = (ent >> 4) & 3, ch = ent >> 6;
        int k0 = ch * 32 + quad * 8;
        f16x8 h;
#pragma unroll
        for (int e = 0; e < 8; e++) {
            int k = k0 + e;
            float kv = (k < DD) ? kern[p * DD + k] : 0.f;
            h[e] = (_Float16)(kv * kv);
        }
        *(f16x8*)&ksqt[ent * 8] = h;
    }
}

// ---------------- maxsim: fused cast+norms+GEMM+max --------------------------------------
// block (b, iw, jw): A = f16(s1[i0..i0+64)), B = f16(s2[j0..j0+48)) staged (cast in-flight)
// into 75 KB LDS -> 2 blocks/CU; 4 waves each own 4 p's over the full 64i x 48j tile.
// (256,2): 2 blocks/CU -> 8 waves/CU -> 256-VGPR cap (the 512-thread variants pinned the
// allocator at 128 VGPRs and spilled ~170 MB; this config family measured clean in R5).
__global__ __launch_bounds__(256, 2) void maxsim_kernel(const float* __restrict__ s1,
                                                        const float* __restrict__ s2,
                                                        const _Float16* __restrict__ ksqt,
                                                        float* __restrict__ part) {
    extern __shared__ __align__(16) char smem[];
    _Float16* h1s = (_Float16*)smem;        // 64*PS halfs
    _Float16* h2s = h1s + 64 * PS;          // 48*PS halfs
    _Float16* n2s = h2s + 48 * PS;          // [48][16] f16

    const int blk = blockIdx.x;
    const int b   = blk / 20;
    const int rr  = blk - b * 20;
    const int iw  = rr / 5;
    const int jw  = rr - iw * 5;
    const int i0  = (iw < 3) ? iw * 64 : 136;   // windows cover 0..199, overlap ok
    const int j0  = (jw < 4) ? jw * 48 : 152;
    const int t   = threadIdx.x;

    // ---- stage + cast: 112 rows x 40 f16x8 groups (wave-aligned row split at idx 2560)
    for (int idx = t; idx < 112 * 40; idx += 256) {
        int lr = idx / 40, q = idx - lr * 40, k0 = q * 8;
        const float* src;
        _Float16* dst;
        if (lr < 64) { src = s1 + ((size_t)b * LL + i0 + lr) * DD;      dst = &h1s[lr * PS + k0]; }
        else         { src = s2 + ((size_t)b * LL + j0 + lr - 64) * DD; dst = &h2s[(lr - 64) * PS + k0]; }
        f16x8 h;
        if (k0 + 8 <= DD) {
            float4 u = *(const float4*)&src[k0];
            float4 v = *(const float4*)&src[k0 + 4];
            h[0] = (_Float16)u.x; h[1] = (_Float16)u.y; h[2] = (_Float16)u.z; h[3] = (_Float16)u.w;
            h[4] = (_Float16)v.x; h[5] = (_Float16)v.y; h[6] = (_Float16)v.z; h[7] = (_Float16)v.w;
        } else if (k0 < DD) {   // k0 == 296
            float4 u = *(const float4*)&src[k0];
            h[0] = (_Float16)u.x; h[1] = (_Float16)u.y; h[2] = (_Float16)u.z; h[3] = (_Float16)u.w;
            h[4] = (_Float16)0.f; h[5] = (_Float16)0.f; h[6] = (_Float16)0.f; h[7] = (_Float16)0.f;
        } else {
#pragma unroll
            for (int e = 0; e < 8; e++) h[e] = (_Float16)0.f;
        }
        *(f16x8*)dst = h;
    }
    __syncthreads();

    const int lane = t & 63;
    const int w    = t >> 6;     // wave owns p in [4w, 4w+4)
    const int c    = lane & 15;
    const int quad = lane >> 4;

    // ---- i-norms via MFMA of squares: lane (c=p, quad) gets rows it*16+quad*4+r ----
    float n1r[4][4];
    {
        f32x4v na[4];
#pragma unroll
        for (int it = 0; it < 4; it++) na[it] = (f32x4v)0.f;
#pragma unroll
        for (int ch = 0; ch < NCH; ch++) {
            f16x8 kb = *(const f16x8*)&ksqt[((ch * 4 + quad) * 16 + c) * 8];
#pragma unroll
            for (int it = 0; it < 4; it++) {
                f16x8 a = *(const f16x8*)&h1s[(it * 16 + c) * PS + ch * 32 + quad * 8];
                na[it] = MFMA16(a * a, kb, na[it]);
            }
        }
#pragma unroll
        for (int it = 0; it < 4; it++)
#pragma unroll
            for (int r = 0; r < 4; r++) n1r[it][r] = rsqrtf(fmaxf(na[it][r], EPSV));
    }
    // ---- j-norms: waves 0..2 own jt=w ----
    if (w < 3) {
        f32x4v na = (f32x4v)0.f;
#pragma unroll
        for (int ch = 0; ch < NCH; ch++) {
            f16x8 kb = *(const f16x8*)&ksqt[((ch * 4 + quad) * 16 + c) * 8];
            f16x8 bq = *(const f16x8*)&h2s[(w * 16 + c) * PS + ch * 32 + quad * 8];
            na = MFMA16(bq * bq, kb, na);
        }
#pragma unroll
        for (int r = 0; r < 4; r++)
            n2s[(w * 16 + quad * 4 + r) * 16 + c] = (_Float16)rsqrtf(fmaxf(na[r], EPSV));
    }
    __syncthreads();

    // ---- main: 2 p-pairs per wave; acc[pq][it][jt] = 24 f32x4 (96 VGPRs) ----
    for (int pp = 0; pp < 2; pp++) {
        const int p0 = w * 4 + pp * 2;
        f32x4v acc[2][4][3];
#pragma unroll
        for (int pq = 0; pq < 2; pq++)
#pragma unroll
            for (int it = 0; it < 4; it++)
#pragma unroll
                for (int jt = 0; jt < 3; jt++) acc[pq][it][jt] = (f32x4v)0.f;

        f16x8 kqn0 = *(const f16x8*)&ksqt[(quad * 16 + p0) * 8];
        f16x8 kqn1 = *(const f16x8*)&ksqt[(quad * 16 + p0 + 1) * 8];

#pragma unroll
        for (int ch = 0; ch < NCH; ch++) {
            f16x8 kq0 = kqn0, kq1 = kqn1;
            if (ch < NCH - 1) {   // rolling prefetch of the L1-hot 10 KB table
                kqn0 = *(const f16x8*)&ksqt[(((ch + 1) * 4 + quad) * 16 + p0) * 8];
                kqn1 = *(const f16x8*)&ksqt[(((ch + 1) * 4 + quad) * 16 + p0 + 1) * 8];
            }
            f16x8 a[4];
#pragma unroll
            for (int it = 0; it < 4; it++)
                a[it] = *(const f16x8*)&h1s[(it * 16 + c) * PS + ch * 32 + quad * 8];
#pragma unroll
            for (int jt = 0; jt < 3; jt++) {
                f16x8 hb  = *(const f16x8*)&h2s[(jt * 16 + c) * PS + ch * 32 + quad * 8];
                f16x8 sb0 = hb * kq0;
                f16x8 sb1 = hb * kq1;
#pragma unroll
                for (int it = 0; it < 4; it++) {
                    acc[0][it][jt] = MFMA16(a[it], sb0, acc[0][it][jt]);
                    acc[1][it][jt] = MFMA16(a[it], sb1, acc[1][it][jt]);
                }
            }
        }

        // ---- epilogue: scale by n2, max over j, apply n1, coalesced p-major store ----
        float rmax[2][4][4];
#pragma unroll
        for (int pq = 0; pq < 2; pq++)
#pragma unroll
            for (int it = 0; it < 4; it++)
#pragma unroll
                for (int r = 0; r < 4; r++) rmax[pq][it][r] = -INFINITY;

#pragma unroll
        for (int pq = 0; pq < 2; pq++)
#pragma unroll
            for (int jt = 0; jt < 3; jt++) {
                float n2 = (float)n2s[(jt * 16 + c) * 16 + p0 + pq];
#pragma unroll
                for (int it = 0; it < 4; it++)
#pragma unroll
                    for (int r = 0; r < 4; r++)
                        rmax[pq][it][r] = fmaxf(rmax[pq][it][r], acc[pq][it][jt][r] * n2);
            }
#pragma unroll
        for (int m = 1; m <= 8; m <<= 1)
#pragma unroll
            for (int pq = 0; pq < 2; pq++)
#pragma unroll
                for (int it = 0; it < 4; it++)
#pragma unroll
                    for (int r = 0; r < 4; r++)
                        rmax[pq][it][r] = fmaxf(rmax[pq][it][r], __shfl_xor(rmax[pq][it][r], m));

#pragma unroll
        for (int pq = 0; pq < 2; pq++) {
            const int p = p0 + pq;
            if (c == p) {   // 4 lanes (quads); part layout [jw][b][p][i] -> float4 stores
#pragma unroll
                for (int it = 0; it < 4; it++) {
                    float4 v = make_float4(rmax[pq][it][0] * n1r[it][0],
                                           rmax[pq][it][1] * n1r[it][1],
                                           rmax[pq][it][2] * n1r[it][2],
                                           rmax[pq][it][3] * n1r[it][3]);
                    *(float4*)&part[(((size_t)jw * BBATCH + b) * PP + p) * LL +
                                    i0 + it * 16 + quad * 4] = v;
                }
            }
        }
    }
}

// ---------------- reduce: out[b,i,p] = max over 5 j-windows of part[jw][b][p][i] --------
__global__ __launch_bounds__(256) void reduce_kernel(const float* __restrict__ part,
                                                     float* __restrict__ out) {
    int tid = blockIdx.x * 256 + threadIdx.x;
    if (tid >= BBATCH * LL * PP) return;
    int b   = tid / (LL * PP);
    int rem = tid - b * (LL * PP);
    int i   = rem >> 4;
    int p   = rem & 15;
    float m = -INFINITY;
#pragma unroll
    for (int jw = 0; jw < 5; jw++)
        m = fmaxf(m, part[(((size_t)jw * BBATCH + b) * PP + p) * LL + i]);
    out[tid] = m;
}

extern "C" void kernel_launch(void* const* d_in, const int* in_sizes, int n_in,
                              void* d_out, int out_size, void* d_ws, size_t ws_size,
                              hipStream_t stream) {
    const float* sent1  = (const float*)d_in[0];   // (64,200,300) f32
    const float* sent2  = (const float*)d_in[1];   // (64,200,300) f32
    const float* kernel = (const float*)d_in[2];   // (16,300)     f32
    float* out = (float*)d_out;                    // (64,200,16)  f32

    char* ws = (char*)d_ws;
    _Float16* ksqt = (_Float16*)ws;  ws += 640 * 8 * 2;          // 10 KB
    float*    part = (float*)ws;     // 5*64*16*200 f32 = 16.4 MB

    ksq_kernel<<<1, 256, 0, stream>>>(kernel, ksqt);

    const int lds_bytes = (64 * PS + 48 * PS + 48 * PP) * 2;     // 75,008 B -> 2 blocks/CU
    hipFuncSetAttribute((const void*)maxsim_kernel,
                        hipFuncAttributeMaxDynamicSharedMemorySize, lds_bytes);
    maxsim_kernel<<<dim3(BBATCH * 20, 1, 1), 256, lds_bytes, stream>>>(sent1, sent2, ksqt, part);

    int nout = BBATCH * LL * PP;
    reduce_kernel<<<(nout + 255) / 256, 256, 0, stream>>>(part, out);
}

// Round 10
// 211.122 us; speedup vs baseline: 1.2709x; 1.2709x over previous
//
#include <hip/hip_runtime.h>
#include <math.h>

#define BBATCH 64
#define LL 200
#define DD 300
#define PP 16
#define EPSV 1e-12f
#define PS 328      // LDS row stride in halfs (656 B); b128 reads spread 4 consecutive banks
#define NCH 10      // K chunks of 32 (K padded 300->320)

typedef _Float16 f16x8 __attribute__((ext_vector_type(8)));
typedef float f32x4v __attribute__((ext_vector_type(4)));

#define MFMA16(A, B, C) __builtin_amdgcn_mfma_f32_16x16x32_f16((A), (B), (C), 0, 0, 0)

// ---------------- ksq table: ksqt[((ch*4+quad)*16+p)*8+e] = f16(kp[p][ch*32+quad*8+e]^2)
__global__ __launch_bounds__(256) void ksq_kernel(const float* __restrict__ kern,
                                                  _Float16* __restrict__ ksqt) {
    for (int ent = threadIdx.x; ent < 640; ent += 256) {
        int p = ent & 15, quad = (ent >> 4) & 3, ch = ent >> 6;
        int k0 = ch * 32 + quad * 8;
        f16x8 h;
#pragma unroll
        for (int e = 0; e < 8; e++) {
            int k = k0 + e;
            float kv = (k < DD) ? kern[p * DD + k] : 0.f;
            h[e] = (_Float16)(kv * kv);
        }
        *(f16x8*)&ksqt[ent * 8] = h;
    }
}

// ---------------- maxsim: fused cast+norms+GEMM+max --------------------------------------
// block (b, iw, jw): A = f16(s1[i0..i0+64)), B = f16(s2[j0..j0+48)) staged (cast in-flight)
// into 75 KB LDS; 4 waves each own 4 p's over the full 64i x 48j tile.
// __launch_bounds__(256, 1): the ONLY config measured to yield a 256-VGPR allocation
// (R5). Every arg2>=2 / 8-wave variant (R6-R9) landed in the 128-VGPR bucket and spilled
// 170-260 MB to scratch. With 75 KB LDS and <=256 VGPRs the HW still co-schedules
// 2 blocks/CU (150 KB LDS, 2x256 VGPR = the full 512/SIMD pool) — occupancy comes from
// resource arithmetic, not from the hint.
__global__ __launch_bounds__(256, 1) void maxsim_kernel(const float* __restrict__ s1,
                                                        const float* __restrict__ s2,
                                                        const _Float16* __restrict__ ksqt,
                                                        float* __restrict__ part) {
    extern __shared__ __align__(16) char smem[];
    _Float16* h1s = (_Float16*)smem;        // 64*PS halfs
    _Float16* h2s = h1s + 64 * PS;          // 48*PS halfs
    _Float16* n2s = h2s + 48 * PS;          // [48][16] f16

    const int blk = blockIdx.x;
    const int b   = blk / 20;
    const int rr  = blk - b * 20;
    const int iw  = rr / 5;
    const int jw  = rr - iw * 5;
    const int i0  = (iw < 3) ? iw * 64 : 136;   // windows cover 0..199, overlap ok
    const int j0  = (jw < 4) ? jw * 48 : 152;
    const int t   = threadIdx.x;

    // ---- stage + cast: 112 rows x 40 f16x8 groups (wave-aligned row split at idx 2560)
    for (int idx = t; idx < 112 * 40; idx += 256) {
        int lr = idx / 40, q = idx - lr * 40, k0 = q * 8;
        const float* src;
        _Float16* dst;
        if (lr < 64) { src = s1 + ((size_t)b * LL + i0 + lr) * DD;      dst = &h1s[lr * PS + k0]; }
        else         { src = s2 + ((size_t)b * LL + j0 + lr - 64) * DD; dst = &h2s[(lr - 64) * PS + k0]; }
        f16x8 h;
        if (k0 + 8 <= DD) {
            float4 u = *(const float4*)&src[k0];
            float4 v = *(const float4*)&src[k0 + 4];
            h[0] = (_Float16)u.x; h[1] = (_Float16)u.y; h[2] = (_Float16)u.z; h[3] = (_Float16)u.w;
            h[4] = (_Float16)v.x; h[5] = (_Float16)v.y; h[6] = (_Float16)v.z; h[7] = (_Float16)v.w;
        } else if (k0 < DD) {   // k0 == 296
            float4 u = *(const float4*)&src[k0];
            h[0] = (_Float16)u.x; h[1] = (_Float16)u.y; h[2] = (_Float16)u.z; h[3] = (_Float16)u.w;
            h[4] = (_Float16)0.f; h[5] = (_Float16)0.f; h[6] = (_Float16)0.f; h[7] = (_Float16)0.f;
        } else {
#pragma unroll
            for (int e = 0; e < 8; e++) h[e] = (_Float16)0.f;
        }
        *(f16x8*)dst = h;
    }
    __syncthreads();

    const int lane = t & 63;
    const int w    = t >> 6;     // wave owns p in [4w, 4w+4)
    const int c    = lane & 15;
    const int quad = lane >> 4;

    // ---- i-norms via MFMA of squares: lane (c=p, quad) gets rows it*16+quad*4+r ----
    float n1r[4][4];
    {
        f32x4v na[4];
#pragma unroll
        for (int it = 0; it < 4; it++) na[it] = (f32x4v)0.f;
#pragma unroll
        for (int ch = 0; ch < NCH; ch++) {
            f16x8 kb = *(const f16x8*)&ksqt[((ch * 4 + quad) * 16 + c) * 8];
#pragma unroll
            for (int it = 0; it < 4; it++) {
                f16x8 a = *(const f16x8*)&h1s[(it * 16 + c) * PS + ch * 32 + quad * 8];
                na[it] = MFMA16(a * a, kb, na[it]);
            }
        }
#pragma unroll
        for (int it = 0; it < 4; it++)
#pragma unroll
            for (int r = 0; r < 4; r++) n1r[it][r] = rsqrtf(fmaxf(na[it][r], EPSV));
    }
    // ---- j-norms: waves 0..2 own jt=w ----
    if (w < 3) {
        f32x4v na = (f32x4v)0.f;
#pragma unroll
        for (int ch = 0; ch < NCH; ch++) {
            f16x8 kb = *(const f16x8*)&ksqt[((ch * 4 + quad) * 16 + c) * 8];
            f16x8 bq = *(const f16x8*)&h2s[(w * 16 + c) * PS + ch * 32 + quad * 8];
            na = MFMA16(bq * bq, kb, na);
        }
#pragma unroll
        for (int r = 0; r < 4; r++)
            n2s[(w * 16 + quad * 4 + r) * 16 + c] = (_Float16)rsqrtf(fmaxf(na[r], EPSV));
    }
    __syncthreads();

    // ---- main: 2 p-pairs per wave; acc[pq][it][jt] = 24 f32x4 (96 VGPRs) ----
    for (int pp = 0; pp < 2; pp++) {
        const int p0 = w * 4 + pp * 2;
        f32x4v acc[2][4][3];
#pragma unroll
        for (int pq = 0; pq < 2; pq++)
#pragma unroll
            for (int it = 0; it < 4; it++)
#pragma unroll
                for (int jt = 0; jt < 3; jt++) acc[pq][it][jt] = (f32x4v)0.f;

        f16x8 kqn0 = *(const f16x8*)&ksqt[(quad * 16 + p0) * 8];
        f16x8 kqn1 = *(const f16x8*)&ksqt[(quad * 16 + p0 + 1) * 8];

#pragma unroll
        for (int ch = 0; ch < NCH; ch++) {
            f16x8 kq0 = kqn0, kq1 = kqn1;
            if (ch < NCH - 1) {   // rolling prefetch of the L1-hot 10 KB table
                kqn0 = *(const f16x8*)&ksqt[(((ch + 1) * 4 + quad) * 16 + p0) * 8];
                kqn1 = *(const f16x8*)&ksqt[(((ch + 1) * 4 + quad) * 16 + p0 + 1) * 8];
            }
            f16x8 a[4];
#pragma unroll
            for (int it = 0; it < 4; it++)
                a[it] = *(const f16x8*)&h1s[(it * 16 + c) * PS + ch * 32 + quad * 8];
#pragma unroll
            for (int jt = 0; jt < 3; jt++) {
                f16x8 hb  = *(const f16x8*)&h2s[(jt * 16 + c) * PS + ch * 32 + quad * 8];
                f16x8 sb0 = hb * kq0;
                f16x8 sb1 = hb * kq1;
#pragma unroll
                for (int it = 0; it < 4; it++) {
                    acc[0][it][jt] = MFMA16(a[it], sb0, acc[0][it][jt]);
                    acc[1][it][jt] = MFMA16(a[it], sb1, acc[1][it][jt]);
                }
            }
        }

        // ---- epilogue: scale by n2, max over j, apply n1, coalesced p-major store ----
        float rmax[2][4][4];
#pragma unroll
        for (int pq = 0; pq < 2; pq++)
#pragma unroll
            for (int it = 0; it < 4; it++)
#pragma unroll
                for (int r = 0; r < 4; r++) rmax[pq][it][r] = -INFINITY;

#pragma unroll
        for (int pq = 0; pq < 2; pq++)
#pragma unroll
            for (int jt = 0; jt < 3; jt++) {
                float n2 = (float)n2s[(jt * 16 + c) * 16 + p0 + pq];
#pragma unroll
                for (int it = 0; it < 4; it++)
#pragma unroll
                    for (int r = 0; r < 4; r++)
                        rmax[pq][it][r] = fmaxf(rmax[pq][it][r], acc[pq][it][jt][r] * n2);
            }
#pragma unroll
        for (int m = 1; m <= 8; m <<= 1)
#pragma unroll
            for (int pq = 0; pq < 2; pq++)
#pragma unroll
                for (int it = 0; it < 4; it++)
#pragma unroll
                    for (int r = 0; r < 4; r++)
                        rmax[pq][it][r] = fmaxf(rmax[pq][it][r], __shfl_xor(rmax[pq][it][r], m));

#pragma unroll
        for (int pq = 0; pq < 2; pq++) {
            const int p = p0 + pq;
            if (c == p) {   // 4 lanes (quads); part layout [jw][b][p][i] -> float4 stores
#pragma unroll
                for (int it = 0; it < 4; it++) {
                    float4 v = make_float4(rmax[pq][it][0] * n1r[it][0],
                                           rmax[pq][it][1] * n1r[it][1],
                                           rmax[pq][it][2] * n1r[it][2],
                                           rmax[pq][it][3] * n1r[it][3]);
                    *(float4*)&part[(((size_t)jw * BBATCH + b) * PP + p) * LL +
                                    i0 + it * 16 + quad * 4] = v;
                }
            }
        }
    }
}

// ---------------- reduce: out[b,i,p] = max over 5 j-windows of part[jw][b][p][i] --------
__global__ __launch_bounds__(256) void reduce_kernel(const float* __restrict__ part,
                                                     float* __restrict__ out) {
    int tid = blockIdx.x * 256 + threadIdx.x;
    if (tid >= BBATCH * LL * PP) return;
    int b   = tid / (LL * PP);
    int rem = tid - b * (LL * PP);
    int i   = rem >> 4;
    int p   = rem & 15;
    float m = -INFINITY;
#pragma unroll
    for (int jw = 0; jw < 5; jw++)
        m = fmaxf(m, part[(((size_t)jw * BBATCH + b) * PP + p) * LL + i]);
    out[tid] = m;
}

extern "C" void kernel_launch(void* const* d_in, const int* in_sizes, int n_in,
                              void* d_out, int out_size, void* d_ws, size_t ws_size,
                              hipStream_t stream) {
    const float* sent1  = (const float*)d_in[0];   // (64,200,300) f32
    const float* sent2  = (const float*)d_in[1];   // (64,200,300) f32
    const float* kernel = (const float*)d_in[2];   // (16,300)     f32
    float* out = (float*)d_out;                    // (64,200,16)  f32

    char* ws = (char*)d_ws;
    _Float16* ksqt = (_Float16*)ws;  ws += 640 * 8 * 2;          // 10 KB
    float*    part = (float*)ws;     // 5*64*16*200 f32 = 16.4 MB

    ksq_kernel<<<1, 256, 0, stream>>>(kernel, ksqt);

    const int lds_bytes = (64 * PS + 48 * PS + 48 * PP) * 2;     // 75,008 B -> 2 blocks/CU
    hipFuncSetAttribute((const void*)maxsim_kernel,
                        hipFuncAttributeMaxDynamicSharedMemorySize, lds_bytes);
    maxsim_kernel<<<dim3(BBATCH * 20, 1, 1), 256, lds_bytes, stream>>>(sent1, sent2, ksqt, part);

    int nout = BBATCH * LL * PP;
    reduce_kernel<<<(nout + 255) / 256, 256, 0, stream>>>(part, out);
}